// Round 1
// baseline (1415.788 us; speedup 1.0000x reference)
//
#include <hip/hip_runtime.h>

#define D_FEAT 128
#define D4 (D_FEAT / 4)   // 32 float4 per row

// out[n][d] = bias[d], vectorized as float4
__global__ void init_bias_kernel(float4* __restrict__ out,
                                 const float4* __restrict__ bias,
                                 int n4) {
    int i = blockIdx.x * blockDim.x + threadIdx.x;
    if (i < n4) {
        out[i] = bias[i & (D4 - 1)];
    }
}

// 32 threads per edge; each thread handles 4 consecutive features.
__global__ void spmm_edge_kernel(const int* __restrict__ src,
                                 const int* __restrict__ dst,
                                 const float* __restrict__ vals,
                                 const float4* __restrict__ feat,
                                 float* __restrict__ out,
                                 int n_edges) {
    int tid = blockIdx.x * blockDim.x + threadIdx.x;
    int e = tid >> 5;         // edge index
    int lane = tid & 31;      // 0..31, feature chunk
    if (e >= n_edges) return;

    int s = src[e];
    int d = dst[e];
    float v = vals[e];

    float4 f = feat[(size_t)s * D4 + lane];

    float* o = out + (size_t)d * D_FEAT + lane * 4;
    atomicAdd(o + 0, v * f.x);
    atomicAdd(o + 1, v * f.y);
    atomicAdd(o + 2, v * f.z);
    atomicAdd(o + 3, v * f.w);
}

extern "C" void kernel_launch(void* const* d_in, const int* in_sizes, int n_in,
                              void* d_out, int out_size, void* d_ws, size_t ws_size,
                              hipStream_t stream) {
    const int* edge_index = (const int*)d_in[0];    // (2, E) int32
    const float* edge_vals = (const float*)d_in[1]; // (E,)
    const float* features  = (const float*)d_in[2]; // (N, 128)
    const float* bias      = (const float*)d_in[3]; // (128,)

    int E = in_sizes[1];
    const int* src = edge_index;
    const int* dst = edge_index + E;

    float* out = (float*)d_out;

    // 1) init out with bias broadcast
    int n4 = out_size / 4;
    {
        int block = 256;
        int grid = (n4 + block - 1) / block;
        init_bias_kernel<<<grid, block, 0, stream>>>((float4*)out, (const float4*)bias, n4);
    }

    // 2) scatter-add edges
    {
        int block = 256;
        long long total = (long long)E * 32;
        int grid = (int)((total + block - 1) / block);
        spmm_edge_kernel<<<grid, block, 0, stream>>>(src, dst, edge_vals,
                                                     (const float4*)features, out, E);
    }
}

// Round 2
// 364.888 us; speedup vs baseline: 3.8801x; 3.8801x over previous
//
#include <hip/hip_runtime.h>

#define D_FEAT 128
#define D2 (D_FEAT / 2)   // 64 float2 per row
#define D4 (D_FEAT / 4)   // 32 float4 per row

// ---------- sort-based path ----------

__global__ void zero_kernel(int* __restrict__ p, int n) {
    int i = blockIdx.x * blockDim.x + threadIdx.x;
    if (i < n) p[i] = 0;
}

__global__ void hist_kernel(const int* __restrict__ dst, int* __restrict__ counts, int E) {
    int e = blockIdx.x * blockDim.x + threadIdx.x;
    if (e < E) atomicAdd(&counts[dst[e]], 1);
}

// Single-block exclusive scan over n counts -> offsets[0..n], cursors[0..n-1]
__global__ void scan_kernel(const int* __restrict__ counts,
                            int* __restrict__ offsets,
                            int* __restrict__ cursors, int n) {
    __shared__ int sdata[1024];
    int tid = threadIdx.x;
    int per = (n + 1023) / 1024;
    int base = tid * per;
    int sum = 0;
    for (int i = 0; i < per; i++) {
        int idx = base + i;
        if (idx < n) sum += counts[idx];
    }
    sdata[tid] = sum;
    __syncthreads();
    // inclusive Hillis-Steele scan over 1024 partials
    for (int off = 1; off < 1024; off <<= 1) {
        int t = (tid >= off) ? sdata[tid - off] : 0;
        __syncthreads();
        sdata[tid] += t;
        __syncthreads();
    }
    int excl = sdata[tid] - sum;  // exclusive prefix of this thread's chunk
    for (int i = 0; i < per; i++) {
        int idx = base + i;
        if (idx < n) {
            offsets[idx] = excl;
            cursors[idx] = excl;
            excl += counts[idx];
        }
    }
    if (tid == 1023) offsets[n] = sdata[1023];
}

__global__ void scatter_kernel(const int* __restrict__ src,
                               const int* __restrict__ dst,
                               const float* __restrict__ vals,
                               int* __restrict__ cursors,
                               int* __restrict__ ssrc,
                               float* __restrict__ sval, int E) {
    int e = blockIdx.x * blockDim.x + threadIdx.x;
    if (e < E) {
        int d = dst[e];
        int pos = atomicAdd(&cursors[d], 1);
        ssrc[pos] = src[e];
        sval[pos] = vals[e];
    }
}

// One wave (64 lanes) per node; lane l holds features [2l, 2l+1] as float2.
__global__ void gather_kernel(const int* __restrict__ offsets,
                              const int* __restrict__ ssrc,
                              const float* __restrict__ sval,
                              const float2* __restrict__ feat2,
                              const float2* __restrict__ bias2,
                              float2* __restrict__ out2,
                              int n_nodes) {
    int gtid = blockIdx.x * blockDim.x + threadIdx.x;
    int node = gtid >> 6;
    int lane = gtid & 63;
    if (node >= n_nodes) return;

    int beg = offsets[node];
    int end = offsets[node + 1];
    float2 acc = bias2[lane];
    for (int e = beg; e < end; e++) {
        int s = ssrc[e];      // wave-uniform address -> broadcast
        float v = sval[e];
        float2 f = feat2[(size_t)s * D2 + lane];
        acc.x += v * f.x;
        acc.y += v * f.y;
    }
    out2[(size_t)node * D2 + lane] = acc;
}

// ---------- fallback atomic path (round-1) ----------

__global__ void init_bias_kernel(float4* __restrict__ out,
                                 const float4* __restrict__ bias, int n4) {
    int i = blockIdx.x * blockDim.x + threadIdx.x;
    if (i < n4) out[i] = bias[i & (D4 - 1)];
}

__global__ void spmm_edge_kernel(const int* __restrict__ src,
                                 const int* __restrict__ dst,
                                 const float* __restrict__ vals,
                                 const float4* __restrict__ feat,
                                 float* __restrict__ out, int n_edges) {
    int tid = blockIdx.x * blockDim.x + threadIdx.x;
    int e = tid >> 5;
    int lane = tid & 31;
    if (e >= n_edges) return;
    int s = src[e];
    int d = dst[e];
    float v = vals[e];
    float4 f = feat[(size_t)s * D4 + lane];
    float* o = out + (size_t)d * D_FEAT + lane * 4;
    atomicAdd(o + 0, v * f.x);
    atomicAdd(o + 1, v * f.y);
    atomicAdd(o + 2, v * f.z);
    atomicAdd(o + 3, v * f.w);
}

extern "C" void kernel_launch(void* const* d_in, const int* in_sizes, int n_in,
                              void* d_out, int out_size, void* d_ws, size_t ws_size,
                              hipStream_t stream) {
    const int* edge_index = (const int*)d_in[0];    // (2, E) int32
    const float* edge_vals = (const float*)d_in[1]; // (E,)
    const float* features  = (const float*)d_in[2]; // (N, 128)
    const float* bias      = (const float*)d_in[3]; // (128,)

    int E = in_sizes[1];
    int N = in_sizes[2] / D_FEAT;
    const int* src = edge_index;
    const int* dst = edge_index + E;
    float* out = (float*)d_out;

    // workspace layout: offsets[N+1] | cursors[N] | counts[N] | ssrc[E] | sval[E]
    size_t needed = ((size_t)3 * N + 1 + (size_t)2 * E) * sizeof(int);

    if (ws_size >= needed) {
        int* offsets = (int*)d_ws;
        int* cursors = offsets + (N + 1);
        int* counts  = cursors + N;
        int* ssrc    = counts + N;
        float* sval  = (float*)(ssrc + E);

        {
            int block = 256, grid = (N + block - 1) / block;
            zero_kernel<<<grid, block, 0, stream>>>(counts, N);
        }
        {
            int block = 256, grid = (E + block - 1) / block;
            hist_kernel<<<grid, block, 0, stream>>>(dst, counts, E);
        }
        scan_kernel<<<1, 1024, 0, stream>>>(counts, offsets, cursors, N);
        {
            int block = 256, grid = (E + block - 1) / block;
            scatter_kernel<<<grid, block, 0, stream>>>(src, dst, edge_vals,
                                                       cursors, ssrc, sval, E);
        }
        {
            long long total = (long long)N * 64;
            int block = 256;
            int grid = (int)((total + block - 1) / block);
            gather_kernel<<<grid, block, 0, stream>>>(offsets, ssrc, sval,
                                                      (const float2*)features,
                                                      (const float2*)bias,
                                                      (float2*)out, N);
        }
    } else {
        // fallback: atomic scatter-add
        int n4 = out_size / 4;
        {
            int block = 256, grid = (n4 + block - 1) / block;
            init_bias_kernel<<<grid, block, 0, stream>>>((float4*)out,
                                                         (const float4*)bias, n4);
        }
        {
            int block = 256;
            long long total = (long long)E * 32;
            int grid = (int)((total + block - 1) / block);
            spmm_edge_kernel<<<grid, block, 0, stream>>>(src, dst, edge_vals,
                                                         (const float4*)features,
                                                         out, E);
        }
    }
}

// Round 3
// 250.759 us; speedup vs baseline: 5.6460x; 1.4551x over previous
//
#include <hip/hip_runtime.h>

#define D_FEAT 128
#define D2 (D_FEAT / 2)   // 64 float2 per row
#define D4 (D_FEAT / 4)   // 32 float4 per row
#define SCAN_BLOCK 256

// ---------- sort-based path ----------

__global__ void zero_kernel(int* __restrict__ p, int n) {
    int i = blockIdx.x * blockDim.x + threadIdx.x;
    if (i < n) p[i] = 0;
}

__global__ void hist_kernel(const int* __restrict__ dst, int* __restrict__ counts, int E) {
    int e = blockIdx.x * blockDim.x + threadIdx.x;
    if (e < E) atomicAdd(&counts[dst[e]], 1);
}

// Per-block reduction of counts -> blocksums[blockIdx]
__global__ void block_sums_kernel(const int* __restrict__ counts,
                                  int* __restrict__ blocksums, int n) {
    __shared__ int sdata[SCAN_BLOCK];
    int tid = threadIdx.x;
    int i = blockIdx.x * SCAN_BLOCK + tid;
    sdata[tid] = (i < n) ? counts[i] : 0;
    __syncthreads();
    for (int off = SCAN_BLOCK / 2; off > 0; off >>= 1) {
        if (tid < off) sdata[tid] += sdata[tid + off];
        __syncthreads();
    }
    if (tid == 0) blocksums[blockIdx.x] = sdata[0];
}

// Single block: exclusive scan of nb blocksums, in place.
__global__ void scan_sums_kernel(int* __restrict__ blocksums, int nb) {
    __shared__ int sdata[SCAN_BLOCK];
    int tid = threadIdx.x;
    int v = (tid < nb) ? blocksums[tid] : 0;
    sdata[tid] = v;
    __syncthreads();
    for (int off = 1; off < SCAN_BLOCK; off <<= 1) {
        int t = (tid >= off) ? sdata[tid - off] : 0;
        __syncthreads();
        sdata[tid] += t;
        __syncthreads();
    }
    if (tid < nb) blocksums[tid] = sdata[tid] - v;  // exclusive
}

// Per-block local exclusive scan + blockbase -> offsets, cursors.
__global__ void local_scan_kernel(const int* __restrict__ counts,
                                  const int* __restrict__ blocksums,
                                  int* __restrict__ offsets,
                                  int* __restrict__ cursors, int n, int total) {
    __shared__ int sdata[SCAN_BLOCK];
    int tid = threadIdx.x;
    int i = blockIdx.x * SCAN_BLOCK + tid;
    int v = (i < n) ? counts[i] : 0;
    sdata[tid] = v;
    __syncthreads();
    for (int off = 1; off < SCAN_BLOCK; off <<= 1) {
        int t = (tid >= off) ? sdata[tid - off] : 0;
        __syncthreads();
        sdata[tid] += t;
        __syncthreads();
    }
    if (i < n) {
        int off = blocksums[blockIdx.x] + sdata[tid] - v;  // exclusive prefix
        offsets[i] = off;
        cursors[i] = off;
    }
    if (blockIdx.x == 0 && tid == 0) offsets[n] = total;
}

__global__ void scatter_kernel(const int* __restrict__ src,
                               const int* __restrict__ dst,
                               const float* __restrict__ vals,
                               int* __restrict__ cursors,
                               int2* __restrict__ spack, int E) {
    int e = blockIdx.x * blockDim.x + threadIdx.x;
    if (e < E) {
        int d = dst[e];
        int pos = atomicAdd(&cursors[d], 1);
        int2 p;
        p.x = src[e];
        p.y = __float_as_int(vals[e]);
        spack[pos] = p;
    }
}

// One wave (64 lanes) per node; lane l holds features [2l, 2l+1] as float2.
__global__ void gather_kernel(const int* __restrict__ offsets,
                              const int2* __restrict__ spack,
                              const float2* __restrict__ feat2,
                              const float2* __restrict__ bias2,
                              float2* __restrict__ out2,
                              int n_nodes) {
    int gtid = blockIdx.x * blockDim.x + threadIdx.x;
    int node = gtid >> 6;
    int lane = gtid & 63;
    if (node >= n_nodes) return;

    int beg = offsets[node];
    int end = offsets[node + 1];
    float2 acc = bias2[lane];
    for (int e = beg; e < end; e++) {
        int2 p = spack[e];             // wave-uniform -> broadcast
        int s = p.x;
        float v = __int_as_float(p.y);
        float2 f = feat2[(size_t)s * D2 + lane];
        acc.x += v * f.x;
        acc.y += v * f.y;
    }
    out2[(size_t)node * D2 + lane] = acc;
}

// ---------- fallback atomic path ----------

__global__ void init_bias_kernel(float4* __restrict__ out,
                                 const float4* __restrict__ bias, int n4) {
    int i = blockIdx.x * blockDim.x + threadIdx.x;
    if (i < n4) out[i] = bias[i & (D4 - 1)];
}

__global__ void spmm_edge_kernel(const int* __restrict__ src,
                                 const int* __restrict__ dst,
                                 const float* __restrict__ vals,
                                 const float4* __restrict__ feat,
                                 float* __restrict__ out, int n_edges) {
    int tid = blockIdx.x * blockDim.x + threadIdx.x;
    int e = tid >> 5;
    int lane = tid & 31;
    if (e >= n_edges) return;
    int s = src[e];
    int d = dst[e];
    float v = vals[e];
    float4 f = feat[(size_t)s * D4 + lane];
    float* o = out + (size_t)d * D_FEAT + lane * 4;
    atomicAdd(o + 0, v * f.x);
    atomicAdd(o + 1, v * f.y);
    atomicAdd(o + 2, v * f.z);
    atomicAdd(o + 3, v * f.w);
}

extern "C" void kernel_launch(void* const* d_in, const int* in_sizes, int n_in,
                              void* d_out, int out_size, void* d_ws, size_t ws_size,
                              hipStream_t stream) {
    const int* edge_index = (const int*)d_in[0];    // (2, E) int32
    const float* edge_vals = (const float*)d_in[1]; // (E,)
    const float* features  = (const float*)d_in[2]; // (N, 128)
    const float* bias      = (const float*)d_in[3]; // (128,)

    int E = in_sizes[1];
    int N = in_sizes[2] / D_FEAT;
    const int* src = edge_index;
    const int* dst = edge_index + E;
    float* out = (float*)d_out;

    int NB = (N + SCAN_BLOCK - 1) / SCAN_BLOCK;

    // workspace layout (spack first for 8B alignment):
    // spack[E] (int2) | offsets[N+1] | cursors[N] | counts[N] | blocksums[NB]
    size_t needed = ((size_t)2 * E + 3 * N + 1 + NB) * sizeof(int);

    if (ws_size >= needed && NB <= SCAN_BLOCK) {
        int2* spack  = (int2*)d_ws;
        int* offsets = (int*)(spack + E);
        int* cursors = offsets + (N + 1);
        int* counts  = cursors + N;
        int* blocksums = counts + N;

        {
            int block = 256, grid = (N + block - 1) / block;
            zero_kernel<<<grid, block, 0, stream>>>(counts, N);
        }
        {
            int block = 256, grid = (E + block - 1) / block;
            hist_kernel<<<grid, block, 0, stream>>>(dst, counts, E);
        }
        block_sums_kernel<<<NB, SCAN_BLOCK, 0, stream>>>(counts, blocksums, N);
        scan_sums_kernel<<<1, SCAN_BLOCK, 0, stream>>>(blocksums, NB);
        local_scan_kernel<<<NB, SCAN_BLOCK, 0, stream>>>(counts, blocksums,
                                                         offsets, cursors, N, E);
        {
            int block = 256, grid = (E + block - 1) / block;
            scatter_kernel<<<grid, block, 0, stream>>>(src, dst, edge_vals,
                                                       cursors, spack, E);
        }
        {
            long long total = (long long)N * 64;
            int block = 256;
            int grid = (int)((total + block - 1) / block);
            gather_kernel<<<grid, block, 0, stream>>>(offsets, spack,
                                                      (const float2*)features,
                                                      (const float2*)bias,
                                                      (float2*)out, N);
        }
    } else {
        // fallback: atomic scatter-add
        int n4 = out_size / 4;
        {
            int block = 256, grid = (n4 + block - 1) / block;
            init_bias_kernel<<<grid, block, 0, stream>>>((float4*)out,
                                                         (const float4*)bias, n4);
        }
        {
            int block = 256;
            long long total = (long long)E * 32;
            int grid = (int)((total + block - 1) / block);
            spmm_edge_kernel<<<grid, block, 0, stream>>>(src, dst, edge_vals,
                                                         (const float4*)features,
                                                         out, E);
        }
    }
}

// Round 4
// 223.844 us; speedup vs baseline: 6.3249x; 1.1202x over previous
//
#include <hip/hip_runtime.h>

#define D_FEAT 128
#define D2 (D_FEAT / 2)   // 64 float2 per row
#define D4 (D_FEAT / 4)   // 32 float4 per row
#define SCAN_BLOCK 256

// ---------- sort-based path ----------

__global__ void zero_kernel(int* __restrict__ p, int n) {
    int i = blockIdx.x * blockDim.x + threadIdx.x;
    if (i < n) p[i] = 0;
}

__global__ void hist_kernel(const int* __restrict__ dst, int* __restrict__ counts, int E) {
    int e = blockIdx.x * blockDim.x + threadIdx.x;
    if (e < E) atomicAdd(&counts[dst[e]], 1);
}

// Per-block reduction of counts -> blocksums[blockIdx]
__global__ void block_sums_kernel(const int* __restrict__ counts,
                                  int* __restrict__ blocksums, int n) {
    __shared__ int sdata[SCAN_BLOCK];
    int tid = threadIdx.x;
    int i = blockIdx.x * SCAN_BLOCK + tid;
    sdata[tid] = (i < n) ? counts[i] : 0;
    __syncthreads();
    for (int off = SCAN_BLOCK / 2; off > 0; off >>= 1) {
        if (tid < off) sdata[tid] += sdata[tid + off];
        __syncthreads();
    }
    if (tid == 0) blocksums[blockIdx.x] = sdata[0];
}

// Single block: exclusive scan of nb blocksums, in place.
__global__ void scan_sums_kernel(int* __restrict__ blocksums, int nb) {
    __shared__ int sdata[SCAN_BLOCK];
    int tid = threadIdx.x;
    int v = (tid < nb) ? blocksums[tid] : 0;
    sdata[tid] = v;
    __syncthreads();
    for (int off = 1; off < SCAN_BLOCK; off <<= 1) {
        int t = (tid >= off) ? sdata[tid - off] : 0;
        __syncthreads();
        sdata[tid] += t;
        __syncthreads();
    }
    if (tid < nb) blocksums[tid] = sdata[tid] - v;  // exclusive
}

// Per-block local exclusive scan + blockbase -> offsets, cursors.
__global__ void local_scan_kernel(const int* __restrict__ counts,
                                  const int* __restrict__ blocksums,
                                  int* __restrict__ offsets,
                                  int* __restrict__ cursors, int n, int total) {
    __shared__ int sdata[SCAN_BLOCK];
    int tid = threadIdx.x;
    int i = blockIdx.x * SCAN_BLOCK + tid;
    int v = (i < n) ? counts[i] : 0;
    sdata[tid] = v;
    __syncthreads();
    for (int off = 1; off < SCAN_BLOCK; off <<= 1) {
        int t = (tid >= off) ? sdata[tid - off] : 0;
        __syncthreads();
        sdata[tid] += t;
        __syncthreads();
    }
    if (i < n) {
        int off = blocksums[blockIdx.x] + sdata[tid] - v;  // exclusive prefix
        offsets[i] = off;
        cursors[i] = off;
    }
    if (blockIdx.x == 0 && tid == 0) offsets[n] = total;
}

__global__ void scatter_kernel(const int* __restrict__ src,
                               const int* __restrict__ dst,
                               const float* __restrict__ vals,
                               int* __restrict__ cursors,
                               int2* __restrict__ spack, int E) {
    int e = blockIdx.x * blockDim.x + threadIdx.x;
    if (e < E) {
        int d = dst[e];
        int pos = atomicAdd(&cursors[d], 1);
        int2 p;
        p.x = src[e];
        p.y = __float_as_int(vals[e]);
        spack[pos] = p;
    }
}

// One wave (64 lanes) per node; lane l holds features [2l, 2l+1] as float2.
// Unrolled x4 with two accumulators to keep 4 independent feature loads in
// flight per wave (latency-bound loop -> MLP).
__global__ void gather_kernel(const int* __restrict__ offsets,
                              const int2* __restrict__ spack,
                              const float2* __restrict__ feat2,
                              const float2* __restrict__ bias2,
                              float2* __restrict__ out2,
                              int n_nodes) {
    int gtid = blockIdx.x * blockDim.x + threadIdx.x;
    int node = gtid >> 6;
    int lane = gtid & 63;
    if (node >= n_nodes) return;

    int beg = offsets[node];
    int end = offsets[node + 1];
    float2 acc0 = bias2[lane];
    float2 acc1 = make_float2(0.f, 0.f);

    int e = beg;
    for (; e + 4 <= end; e += 4) {
        int2 p0 = spack[e + 0];
        int2 p1 = spack[e + 1];
        int2 p2 = spack[e + 2];
        int2 p3 = spack[e + 3];
        float2 f0 = feat2[(size_t)p0.x * D2 + lane];
        float2 f1 = feat2[(size_t)p1.x * D2 + lane];
        float2 f2 = feat2[(size_t)p2.x * D2 + lane];
        float2 f3 = feat2[(size_t)p3.x * D2 + lane];
        float v0 = __int_as_float(p0.y);
        float v1 = __int_as_float(p1.y);
        float v2 = __int_as_float(p2.y);
        float v3 = __int_as_float(p3.y);
        acc0.x += v0 * f0.x; acc0.y += v0 * f0.y;
        acc1.x += v1 * f1.x; acc1.y += v1 * f1.y;
        acc0.x += v2 * f2.x; acc0.y += v2 * f2.y;
        acc1.x += v3 * f3.x; acc1.y += v3 * f3.y;
    }
    for (; e < end; e++) {
        int2 p = spack[e];
        float v = __int_as_float(p.y);
        float2 f = feat2[(size_t)p.x * D2 + lane];
        acc0.x += v * f.x; acc0.y += v * f.y;
    }
    acc0.x += acc1.x; acc0.y += acc1.y;
    out2[(size_t)node * D2 + lane] = acc0;
}

// ---------- fallback atomic path ----------

__global__ void init_bias_kernel(float4* __restrict__ out,
                                 const float4* __restrict__ bias, int n4) {
    int i = blockIdx.x * blockDim.x + threadIdx.x;
    if (i < n4) out[i] = bias[i & (D4 - 1)];
}

__global__ void spmm_edge_kernel(const int* __restrict__ src,
                                 const int* __restrict__ dst,
                                 const float* __restrict__ vals,
                                 const float4* __restrict__ feat,
                                 float* __restrict__ out, int n_edges) {
    int tid = blockIdx.x * blockDim.x + threadIdx.x;
    int e = tid >> 5;
    int lane = tid & 31;
    if (e >= n_edges) return;
    int s = src[e];
    int d = dst[e];
    float v = vals[e];
    float4 f = feat[(size_t)s * D4 + lane];
    float* o = out + (size_t)d * D_FEAT + lane * 4;
    atomicAdd(o + 0, v * f.x);
    atomicAdd(o + 1, v * f.y);
    atomicAdd(o + 2, v * f.z);
    atomicAdd(o + 3, v * f.w);
}

extern "C" void kernel_launch(void* const* d_in, const int* in_sizes, int n_in,
                              void* d_out, int out_size, void* d_ws, size_t ws_size,
                              hipStream_t stream) {
    const int* edge_index = (const int*)d_in[0];    // (2, E) int32
    const float* edge_vals = (const float*)d_in[1]; // (E,)
    const float* features  = (const float*)d_in[2]; // (N, 128)
    const float* bias      = (const float*)d_in[3]; // (128,)

    int E = in_sizes[1];
    int N = in_sizes[2] / D_FEAT;
    const int* src = edge_index;
    const int* dst = edge_index + E;
    float* out = (float*)d_out;

    int NB = (N + SCAN_BLOCK - 1) / SCAN_BLOCK;

    // workspace layout (spack first for 8B alignment):
    // spack[E] (int2) | offsets[N+1] | cursors[N] | counts[N] | blocksums[NB]
    size_t needed = ((size_t)2 * E + 3 * N + 1 + NB) * sizeof(int);

    if (ws_size >= needed && NB <= SCAN_BLOCK) {
        int2* spack  = (int2*)d_ws;
        int* offsets = (int*)(spack + E);
        int* cursors = offsets + (N + 1);
        int* counts  = cursors + N;
        int* blocksums = counts + N;

        {
            int block = 256, grid = (N + block - 1) / block;
            zero_kernel<<<grid, block, 0, stream>>>(counts, N);
        }
        {
            int block = 256, grid = (E + block - 1) / block;
            hist_kernel<<<grid, block, 0, stream>>>(dst, counts, E);
        }
        block_sums_kernel<<<NB, SCAN_BLOCK, 0, stream>>>(counts, blocksums, N);
        scan_sums_kernel<<<1, SCAN_BLOCK, 0, stream>>>(blocksums, NB);
        local_scan_kernel<<<NB, SCAN_BLOCK, 0, stream>>>(counts, blocksums,
                                                         offsets, cursors, N, E);
        {
            int block = 256, grid = (E + block - 1) / block;
            scatter_kernel<<<grid, block, 0, stream>>>(src, dst, edge_vals,
                                                       cursors, spack, E);
        }
        {
            long long total = (long long)N * 64;
            int block = 256;
            int grid = (int)((total + block - 1) / block);
            gather_kernel<<<grid, block, 0, stream>>>(offsets, spack,
                                                      (const float2*)features,
                                                      (const float2*)bias,
                                                      (float2*)out, N);
        }
    } else {
        // fallback: atomic scatter-add
        int n4 = out_size / 4;
        {
            int block = 256, grid = (n4 + block - 1) / block;
            init_bias_kernel<<<grid, block, 0, stream>>>((float4*)out,
                                                         (const float4*)bias, n4);
        }
        {
            int block = 256;
            long long total = (long long)E * 32;
            int grid = (int)((total + block - 1) / block);
            spmm_edge_kernel<<<grid, block, 0, stream>>>(src, dst, edge_vals,
                                                         (const float4*)features,
                                                         out, E);
        }
    }
}